// Round 5
// baseline (175.503 us; speedup 1.0000x reference)
//
#include <hip/hip_runtime.h>

#define T 200
#define E 64
#define NTILE 13          // 16-row MFMA tiles covering 208 >= 200
#define TPAD 208
#define ROW 72            // bf16 elems per padded sK row (144 B, 16B aligned)
#define MB 16             // batch rows per MLP block

typedef __bf16 bf16_t;
typedef __bf16 bf16x8 __attribute__((ext_vector_type(8)));
typedef float f32x4 __attribute__((ext_vector_type(4)));

// ============================================================
// K1: per-b prep — M in MFMA B-fragment order (bf16) + u vector
// ws layout: wsM[b][512] uint4 chunks; chunk c: f=c>>6 (nt=f>>1,h=f&1),
// lane l=c&63 (n=l&15,quad=l>>4) -> Mt[j=nt*16+n][e=h*32+quad*8 .. +8]
// ============================================================
__global__ __launch_bounds__(256) void prep_kernel(
    const int* __restrict__ query,
    const float* __restrict__ emb,
    const float* __restrict__ w1,
    const float* __restrict__ b1,
    uint4* __restrict__ wsM,
    float* __restrict__ wsU)
{
    __shared__ float sTmp[64 * 65];
    __shared__ __align__(16) float sQ[64];
    __shared__ float sUP[256];

    const int tid = threadIdx.x;
    const int b   = blockIdx.x;

    const int qi = query[b];
    if (tid < 16) ((float4*)sQ)[tid] = ((const float4*)(emb + (size_t)qi * E))[tid];
    __syncthreads();

    // M[e][j] = w1[64+e][j] - w1[128+e][j] + q[e]*w1[192+e][j]  (scratch e*65+j)
    // u[j]    = b1[j] + sum_e q[e]*(w1[e][j] + w1[128+e][j])
    {
        const int j = tid & 63, ec = tid >> 6;
        float au = 0.f;
        #pragma unroll
        for (int eo = 0; eo < 16; ++eo) {
            const int e = ec * 16 + eo;
            const float w1a = w1[e * 64 + j];
            const float w1b = w1[(64 + e) * 64 + j];
            const float w1c = w1[(128 + e) * 64 + j];
            const float w1d = w1[(192 + e) * 64 + j];
            sTmp[e * 65 + j] = w1b - w1c + sQ[e] * w1d;
            au = fmaf(sQ[e], w1a + w1c, au);
        }
        sUP[tid] = au;
    }
    __syncthreads();
    if (tid < 64)
        wsU[(size_t)b * 64 + tid] = b1[tid] + sUP[tid] + sUP[64 + tid] + sUP[128 + tid] + sUP[192 + tid];

    // fragment-order writes (coalesced dwordx4)
    #pragma unroll
    for (int c = tid; c < 512; c += 256) {
        const int f = c >> 6, l = c & 63;
        const int nt = f >> 1, h = f & 1;
        const int n = l & 15, quad = l >> 4;
        const int j2 = nt * 16 + n;
        const int e0 = h * 32 + quad * 8;
        union { bf16_t hh[8]; uint4 v; } u;
        #pragma unroll
        for (int s = 0; s < 8; ++s) u.hh[s] = (bf16_t)sTmp[(e0 + s) * 65 + j2];
        wsM[(size_t)b * 512 + c] = u.v;
    }
}

// ============================================================
// K2: per-b attention — gather k, MFMA scores, softmax, interest
// ============================================================
__global__ __launch_bounds__(256) void main_kernel(
    const int* __restrict__ keys,
    const float* __restrict__ emb,
    const uint4* __restrict__ wsM,
    const float* __restrict__ wsU,
    const float* __restrict__ w2,
    const float* __restrict__ b2,
    float* __restrict__ wsI)
{
    __shared__ __align__(16) bf16_t sK[TPAD * ROW];   // 29952 B
    __shared__ __align__(16) float sU[64];
    __shared__ __align__(16) float sW2f[64];
    __shared__ float sWgt[256];
    __shared__ float sUP[256];
    __shared__ float sRed[8];

    const int tid  = threadIdx.x;
    const int lane = tid & 63;
    const int wid  = tid >> 6;
    const int b    = blockIdx.x;

    // gather this thread's key row (fp32) and cvt to bf16 regs
    uint4 kr[8];
    #pragma unroll
    for (int c = 0; c < 8; ++c) kr[c] = make_uint4(0u, 0u, 0u, 0u);
    if (tid < T) {
        const int ki = keys[b * T + tid];
        const float4* kp = (const float4*)(emb + (size_t)ki * E);
        #pragma unroll
        for (int c = 0; c < 8; ++c) {
            const float4 x = kp[2 * c], y = kp[2 * c + 1];
            union { bf16_t h[8]; uint4 v; } u;
            u.h[0] = (bf16_t)x.x; u.h[1] = (bf16_t)x.y; u.h[2] = (bf16_t)x.z; u.h[3] = (bf16_t)x.w;
            u.h[4] = (bf16_t)y.x; u.h[5] = (bf16_t)y.y; u.h[6] = (bf16_t)y.z; u.h[7] = (bf16_t)y.w;
            kr[c] = u.v;
        }
    }
    if (tid < 16) ((float4*)sU)[tid] = ((const float4*)(wsU + (size_t)b * 64))[tid];
    else if (tid < 32) ((float4*)sW2f)[tid - 16] = ((const float4*)w2)[tid - 16];
    const float b2v = b2[0];

    // B-fragments: coalesced dwordx4 from ws (written in frag order by K1)
    bf16x8 bF[4][2];
    {
        const uint4* mp = wsM + (size_t)b * 512;
        #pragma unroll
        for (int nt = 0; nt < 4; ++nt)
            #pragma unroll
            for (int h = 0; h < 2; ++h) {
                union { uint4 v; bf16x8 f; } u;
                u.v = mp[(nt * 2 + h) * 64 + lane];
                bF[nt][h] = u.f;
            }
    }

    // stage k rows (rows 200..207 zero, rows >=208 none)
    if (tid < TPAD) {
        uint4* dst = (uint4*)(sK + tid * ROW);
        #pragma unroll
        for (int c = 0; c < 8; ++c) dst[c] = kr[c];
    }
    __syncthreads();

    // MFMA score GEMM + relu·w2 epilogue
    {
        const int n    = lane & 15;
        const int quad = lane >> 4;
        float uvv[4], w2v[4];
        #pragma unroll
        for (int nt = 0; nt < 4; ++nt) { uvv[nt] = sU[nt * 16 + n]; w2v[nt] = sW2f[nt * 16 + n]; }
        for (int mt = wid; mt < NTILE; mt += 4) {
            const bf16x8 a0 = *(const bf16x8*)&sK[(mt * 16 + n) * ROW + quad * 8];
            const bf16x8 a1 = *(const bf16x8*)&sK[(mt * 16 + n) * ROW + 32 + quad * 8];
            float s0 = 0.f, s1 = 0.f, s2 = 0.f, s3 = 0.f;
            #pragma unroll
            for (int nt = 0; nt < 4; ++nt) {
                f32x4 acc = { uvv[nt], uvv[nt], uvv[nt], uvv[nt] };
                acc = __builtin_amdgcn_mfma_f32_16x16x32_bf16(a0, bF[nt][0], acc, 0, 0, 0);
                acc = __builtin_amdgcn_mfma_f32_16x16x32_bf16(a1, bF[nt][1], acc, 0, 0, 0);
                s0 = fmaf(fmaxf(acc[0], 0.f), w2v[nt], s0);
                s1 = fmaf(fmaxf(acc[1], 0.f), w2v[nt], s1);
                s2 = fmaf(fmaxf(acc[2], 0.f), w2v[nt], s2);
                s3 = fmaf(fmaxf(acc[3], 0.f), w2v[nt], s3);
            }
            #pragma unroll
            for (int off = 1; off < 16; off <<= 1) {
                s0 += __shfl_xor(s0, off);
                s1 += __shfl_xor(s1, off);
                s2 += __shfl_xor(s2, off);
                s3 += __shfl_xor(s3, off);
            }
            if (n == 0) {
                const int base = mt * 16 + quad * 4;
                sWgt[base + 0] = s0;
                sWgt[base + 1] = s1;
                sWgt[base + 2] = s2;
                sWgt[base + 3] = s3;
            }
        }
    }
    __syncthreads();

    // softmax over t = tid
    {
        const float score = (tid < T) ? (sWgt[tid] + b2v) : -1e30f;
        float m = score;
        #pragma unroll
        for (int off = 32; off > 0; off >>= 1) m = fmaxf(m, __shfl_xor(m, off));
        if (lane == 0) sRed[wid] = m;
        __syncthreads();
        const float gmax = fmaxf(fmaxf(sRed[0], sRed[1]), fmaxf(sRed[2], sRed[3]));
        const float p = (tid < T) ? __expf(score - gmax) : 0.f;
        float s = p;
        #pragma unroll
        for (int off = 32; off > 0; off >>= 1) s += __shfl_xor(s, off);
        if (lane == 0) sRed[4 + wid] = s;
        __syncthreads();
        const float gsum = sRed[4] + sRed[5] + sRed[6] + sRed[7];
        sWgt[tid] = p / gsum;          // 0 for t >= 200
    }
    __syncthreads();

    // interest[e] = sum_t w[t]*k[t][e]
    {
        const int e = tid & 63, ch = tid >> 6;
        float a = 0.f;
        #pragma unroll 4
        for (int tt = 0; tt < 52; ++tt) {
            const int t = ch * 52 + tt;
            a = fmaf(sWgt[t], (float)sK[t * ROW + e], a);
        }
        sUP[tid] = a;
    }
    __syncthreads();
    if (tid < 64)
        wsI[(size_t)b * 64 + tid] = sUP[tid] + sUP[64 + tid] + sUP[128 + tid] + sUP[192 + tid];
}

// ============================================================
// K3: batched deep MLP 64->128->64->1 over MB rows per block
// ============================================================
__global__ __launch_bounds__(256) void mlp_kernel(
    const float* __restrict__ wsI,
    const float* __restrict__ dw1,
    const float* __restrict__ db1,
    const float* __restrict__ dw2,
    const float* __restrict__ db2,
    const float* __restrict__ ow,
    const float* __restrict__ ob,
    float* __restrict__ out,
    int B)
{
    __shared__ __align__(16) float sDW1[64 * 128];   // 32 KB
    __shared__ __align__(16) float sDW2[128 * 64];   // 32 KB
    __shared__ __align__(16) float sI[MB * 68];
    __shared__ __align__(16) float sH1[MB * 132];
    __shared__ __align__(16) float sH2[MB * 68];
    __shared__ float sB1[128];
    __shared__ float sB2[64];
    __shared__ float sOW[64];

    const int tid = threadIdx.x;
    const int b0  = blockIdx.x * MB;

    for (int i = tid; i < 2048; i += 256) ((float4*)sDW1)[i] = ((const float4*)dw1)[i];
    for (int i = tid; i < 2048; i += 256) ((float4*)sDW2)[i] = ((const float4*)dw2)[i];
    if (tid < 128) sB1[tid] = db1[tid];
    if (tid < 64) { sB2[tid] = db2[tid]; sOW[tid] = ow[tid]; }
    {
        const int bi = tid >> 4, e4 = (tid & 15) * 4;
        if (b0 + bi < B) {
            const float4 v = *(const float4*)(wsI + (size_t)(b0 + bi) * 64 + e4);
            *(float4*)&sI[bi * 68 + e4] = v;
        }
    }
    __syncthreads();

    // layer1: h1[bi][j] = relu(b1[j] + sum_e I[bi][e]*dw1[e][j]); j = jb*8+jj
    {
        const int bi = tid >> 4, jb = tid & 15;
        float iv[64];
        #pragma unroll
        for (int e4 = 0; e4 < 16; ++e4) {
            const float4 v = *(const float4*)&sI[bi * 68 + e4 * 4];
            iv[e4 * 4 + 0] = v.x; iv[e4 * 4 + 1] = v.y; iv[e4 * 4 + 2] = v.z; iv[e4 * 4 + 3] = v.w;
        }
        float a[8];
        #pragma unroll
        for (int jj = 0; jj < 8; ++jj) a[jj] = sB1[jb * 8 + jj];
        #pragma unroll 8
        for (int e = 0; e < 64; ++e) {
            const float4 w0 = *(const float4*)&sDW1[e * 128 + jb * 8];
            const float4 w4 = *(const float4*)&sDW1[e * 128 + jb * 8 + 4];
            const float x = iv[e];
            a[0] = fmaf(x, w0.x, a[0]); a[1] = fmaf(x, w0.y, a[1]);
            a[2] = fmaf(x, w0.z, a[2]); a[3] = fmaf(x, w0.w, a[3]);
            a[4] = fmaf(x, w4.x, a[4]); a[5] = fmaf(x, w4.y, a[5]);
            a[6] = fmaf(x, w4.z, a[6]); a[7] = fmaf(x, w4.w, a[7]);
        }
        #pragma unroll
        for (int jj = 0; jj < 4; ++jj) {
            float4 v;
            v.x = fmaxf(a[0 + ((jj & 1) * 4 + (jj >> 1) * 0)], 0.f); // keep simple below
            (void)v;
        }
        // store (two float4s)
        float4 v0, v1;
        v0.x = fmaxf(a[0], 0.f); v0.y = fmaxf(a[1], 0.f); v0.z = fmaxf(a[2], 0.f); v0.w = fmaxf(a[3], 0.f);
        v1.x = fmaxf(a[4], 0.f); v1.y = fmaxf(a[5], 0.f); v1.z = fmaxf(a[6], 0.f); v1.w = fmaxf(a[7], 0.f);
        *(float4*)&sH1[bi * 132 + jb * 8] = v0;
        *(float4*)&sH1[bi * 132 + jb * 8 + 4] = v1;
    }
    __syncthreads();

    // layer2: h2[bi][o] = relu(b2[o] + sum_i h1[bi][i]*dw2[i][o]); o = obb*4+oo
    {
        const int bi = tid >> 4, obb = tid & 15;
        float a0 = sB2[obb * 4 + 0], a1 = sB2[obb * 4 + 1], a2 = sB2[obb * 4 + 2], a3 = sB2[obb * 4 + 3];
        #pragma unroll 4
        for (int i4 = 0; i4 < 32; ++i4) {
            const float4 hv = *(const float4*)&sH1[bi * 132 + i4 * 4];
            const float4 wv0 = *(const float4*)&sDW2[(i4 * 4 + 0) * 64 + obb * 4];
            const float4 wv1 = *(const float4*)&sDW2[(i4 * 4 + 1) * 64 + obb * 4];
            const float4 wv2 = *(const float4*)&sDW2[(i4 * 4 + 2) * 64 + obb * 4];
            const float4 wv3 = *(const float4*)&sDW2[(i4 * 4 + 3) * 64 + obb * 4];
            a0 = fmaf(hv.x, wv0.x, a0); a1 = fmaf(hv.x, wv0.y, a1);
            a2 = fmaf(hv.x, wv0.z, a2); a3 = fmaf(hv.x, wv0.w, a3);
            a0 = fmaf(hv.y, wv1.x, a0); a1 = fmaf(hv.y, wv1.y, a1);
            a2 = fmaf(hv.y, wv1.z, a2); a3 = fmaf(hv.y, wv1.w, a3);
            a0 = fmaf(hv.z, wv2.x, a0); a1 = fmaf(hv.z, wv2.y, a1);
            a2 = fmaf(hv.z, wv2.z, a2); a3 = fmaf(hv.z, wv2.w, a3);
            a0 = fmaf(hv.w, wv3.x, a0); a1 = fmaf(hv.w, wv3.y, a1);
            a2 = fmaf(hv.w, wv3.z, a2); a3 = fmaf(hv.w, wv3.w, a3);
        }
        float4 v;
        v.x = fmaxf(a0, 0.f); v.y = fmaxf(a1, 0.f); v.z = fmaxf(a2, 0.f); v.w = fmaxf(a3, 0.f);
        *(float4*)&sH2[bi * 68 + obb * 4] = v;
    }
    __syncthreads();

    // layer3: out[bi] = sigmoid(sum_o h2[bi][o]*ow[o] + ob)
    if (tid < MB) {
        const int bi = tid;
        float a = 0.f;
        #pragma unroll 8
        for (int o = 0; o < 64; ++o) a = fmaf(sH2[bi * 68 + o], sOW[o], a);
        if (b0 + bi < B) out[b0 + bi] = 1.f / (1.f + __expf(-(a + ob[0])));
    }
}

// ============================================================
// Fallback: round-4 monolithic kernel (used if ws too small)
// ============================================================
__global__ __launch_bounds__(256, 3) void din_mono(
    const int* __restrict__ query,
    const int* __restrict__ keys,
    const float* __restrict__ embf,
    const float* __restrict__ w1,
    const float* __restrict__ b1,
    const float* __restrict__ w2,
    const float* __restrict__ b2,
    const float* __restrict__ dw1,
    const float* __restrict__ db1,
    const float* __restrict__ dw2,
    const float* __restrict__ db2,
    const float* __restrict__ ow,
    const float* __restrict__ ob,
    float* __restrict__ out)
{
    __shared__ __align__(16) char sRaw[256 * ROW * 2];
    __shared__ __align__(16) bf16_t sMt[64 * ROW];
    __shared__ float sU[64];
    __shared__ float sUP[256];
    __shared__ float sW2f[64];
    __shared__ float sWgt[256];
    __shared__ float sQf[64];
    __shared__ float sRed[8];
    __shared__ float sInt[64];
    __shared__ float sD1[128];
    __shared__ float sD2[64];

    const int tid  = threadIdx.x;
    const int lane = tid & 63;
    const int wid  = tid >> 6;
    const int b    = blockIdx.x;
    const float b2v = b2[0];

    uint4 kr[8];
    #pragma unroll
    for (int c = 0; c < 8; ++c) kr[c] = make_uint4(0u, 0u, 0u, 0u);
    if (tid < T) {
        const int ki = keys[b * T + tid];
        const float4* kp = (const float4*)(embf + (size_t)ki * E);
        #pragma unroll
        for (int c = 0; c < 8; ++c) {
            const float4 x = kp[2 * c], y = kp[2 * c + 1];
            union { bf16_t h[8]; uint4 v; } u;
            u.h[0] = (bf16_t)x.x; u.h[1] = (bf16_t)x.y; u.h[2] = (bf16_t)x.z; u.h[3] = (bf16_t)x.w;
            u.h[4] = (bf16_t)y.x; u.h[5] = (bf16_t)y.y; u.h[6] = (bf16_t)y.z; u.h[7] = (bf16_t)y.w;
            kr[c] = u.v;
        }
    }
    const int qi = query[b];
    if (tid < 16) ((float4*)sQf)[tid] = ((const float4*)(embf + (size_t)qi * E))[tid];
    if (tid < 64) sW2f[tid] = w2[tid];
    __syncthreads();

    {
        float* sTmp = (float*)sRaw;
        const int j = tid & 63, ec = tid >> 6;
        float au = 0.f;
        #pragma unroll
        for (int eo = 0; eo < 16; ++eo) {
            const int e = ec * 16 + eo;
            const float w1a = w1[e * 64 + j];
            const float w1b = w1[(64 + e) * 64 + j];
            const float w1c = w1[(128 + e) * 64 + j];
            const float w1d = w1[(192 + e) * 64 + j];
            sTmp[e * 65 + j] = w1b - w1c + sQf[e] * w1d;
            au = fmaf(sQf[e], w1a + w1c, au);
        }
        sUP[tid] = au;
    }
    __syncthreads();
    {
        const float* sTmp = (const float*)sRaw;
        const int e = tid & 63, jc = tid >> 6;
        #pragma unroll
        for (int jo = 0; jo < 16; ++jo) {
            const int j = jc * 16 + jo;
            sMt[j * ROW + e] = (bf16_t)sTmp[e * 65 + j];
        }
    }
    if (tid < 64) sU[tid] = b1[tid] + sUP[tid] + sUP[64 + tid] + sUP[128 + tid] + sUP[192 + tid];
    __syncthreads();

    bf16_t* sK = (bf16_t*)sRaw;
    {
        uint4* dst = (uint4*)(sK + tid * ROW);
        #pragma unroll
        for (int c = 0; c < 8; ++c) dst[c] = kr[c];
    }
    __syncthreads();

    {
        const int n    = lane & 15;
        const int quad = lane >> 4;
        float w2v[4], uv[4];
        bf16x8 bF[4][2];
        #pragma unroll
        for (int nt = 0; nt < 4; ++nt) {
            w2v[nt] = sW2f[nt * 16 + n];
            uv[nt]  = sU[nt * 16 + n];
            bF[nt][0] = *(const bf16x8*)&sMt[(nt * 16 + n) * ROW + quad * 8];
            bF[nt][1] = *(const bf16x8*)&sMt[(nt * 16 + n) * ROW + 32 + quad * 8];
        }
        #pragma unroll
        for (int i = 0; i < 4; ++i) {
            const int mt = wid * 4 + i;
            const bf16x8 a0 = *(const bf16x8*)&sK[(mt * 16 + n) * ROW + quad * 8];
            const bf16x8 a1 = *(const bf16x8*)&sK[(mt * 16 + n) * ROW + 32 + quad * 8];
            float s0 = 0.f, s1 = 0.f, s2 = 0.f, s3 = 0.f;
            #pragma unroll
            for (int nt = 0; nt < 4; ++nt) {
                f32x4 acc = { uv[nt], uv[nt], uv[nt], uv[nt] };
                acc = __builtin_amdgcn_mfma_f32_16x16x32_bf16(a0, bF[nt][0], acc, 0, 0, 0);
                acc = __builtin_amdgcn_mfma_f32_16x16x32_bf16(a1, bF[nt][1], acc, 0, 0, 0);
                s0 = fmaf(fmaxf(acc[0], 0.f), w2v[nt], s0);
                s1 = fmaf(fmaxf(acc[1], 0.f), w2v[nt], s1);
                s2 = fmaf(fmaxf(acc[2], 0.f), w2v[nt], s2);
                s3 = fmaf(fmaxf(acc[3], 0.f), w2v[nt], s3);
            }
            #pragma unroll
            for (int off = 1; off < 16; off <<= 1) {
                s0 += __shfl_xor(s0, off);
                s1 += __shfl_xor(s1, off);
                s2 += __shfl_xor(s2, off);
                s3 += __shfl_xor(s3, off);
            }
            if (n == 0) {
                const int base = mt * 16 + quad * 4;
                sWgt[base + 0] = s0;
                sWgt[base + 1] = s1;
                sWgt[base + 2] = s2;
                sWgt[base + 3] = s3;
            }
        }
    }
    __syncthreads();

    {
        const float score = (tid < T) ? (sWgt[tid] + b2v) : -1e30f;
        float m = score;
        #pragma unroll
        for (int off = 32; off > 0; off >>= 1) m = fmaxf(m, __shfl_xor(m, off));
        if (lane == 0) sRed[wid] = m;
        __syncthreads();
        const float gmax = fmaxf(fmaxf(sRed[0], sRed[1]), fmaxf(sRed[2], sRed[3]));
        const float p = (tid < T) ? __expf(score - gmax) : 0.f;
        float s = p;
        #pragma unroll
        for (int off = 32; off > 0; off >>= 1) s += __shfl_xor(s, off);
        if (lane == 0) sRed[4 + wid] = s;
        __syncthreads();
        const float gsum = sRed[4] + sRed[5] + sRed[6] + sRed[7];
        sWgt[tid] = p / gsum;
    }
    __syncthreads();

    {
        const int e = tid & 63, ch = tid >> 6;
        float a = 0.f;
        #pragma unroll 8
        for (int tt = 0; tt < 64; ++tt) {
            const int t = ch * 64 + tt;
            a = fmaf(sWgt[t], (float)sK[t * ROW + e], a);
        }
        sUP[tid] = a;
    }
    __syncthreads();
    if (tid < 64) sInt[tid] = sUP[tid] + sUP[64 + tid] + sUP[128 + tid] + sUP[192 + tid];
    __syncthreads();

    if (tid < 128) {
        float a = db1[tid];
        #pragma unroll 8
        for (int e = 0; e < 64; ++e) a = fmaf(sInt[e], dw1[e * 128 + tid], a);
        sD1[tid] = fmaxf(a, 0.f);
    }
    __syncthreads();
    if (tid < 64) {
        float a = db2[tid];
        #pragma unroll 8
        for (int i = 0; i < 128; ++i) a = fmaf(sD1[i], dw2[i * 64 + tid], a);
        sD2[tid] = fmaxf(a, 0.f);
    }
    __syncthreads();
    if (tid < 64) {
        float v = sD2[tid] * ow[tid];
        #pragma unroll
        for (int off = 32; off > 0; off >>= 1) v += __shfl_xor(v, off);
        if (tid == 0) out[b] = 1.f / (1.f + __expf(-(v + ob[0])));
    }
}

extern "C" void kernel_launch(void* const* d_in, const int* in_sizes, int n_in,
                              void* d_out, int out_size, void* d_ws, size_t ws_size,
                              hipStream_t stream) {
    const int*   query = (const int*)d_in[0];
    const int*   keys  = (const int*)d_in[1];
    const float* embf  = (const float*)d_in[2];
    const float* w1    = (const float*)d_in[3];
    const float* b1    = (const float*)d_in[4];
    const float* w2    = (const float*)d_in[5];
    const float* b2    = (const float*)d_in[6];
    const float* dw1   = (const float*)d_in[7];
    const float* db1   = (const float*)d_in[8];
    const float* dw2   = (const float*)d_in[9];
    const float* db2   = (const float*)d_in[10];
    const float* ow    = (const float*)d_in[11];
    const float* ob    = (const float*)d_in[12];
    float* out = (float*)d_out;
    const int B = in_sizes[0];

    const size_t needM = (size_t)B * 8192;        // bf16 M frags
    const size_t needU = (size_t)B * 256;         // fp32 u
    const size_t needI = (size_t)B * 256;         // fp32 interest
    if (ws_size >= needM + needU + needI) {
        uint4* wsM = (uint4*)d_ws;
        float* wsU = (float*)((char*)d_ws + needM);
        float* wsI = (float*)((char*)d_ws + needM + needU);
        prep_kernel<<<B, 256, 0, stream>>>(query, embf, w1, b1, wsM, wsU);
        main_kernel<<<B, 256, 0, stream>>>(keys, embf, wsM, wsU, w2, b2, wsI);
        mlp_kernel<<<(B + MB - 1) / MB, 256, 0, stream>>>(wsI, dw1, db1, dw2, db2, ow, ob, out, B);
    } else {
        din_mono<<<B, 256, 0, stream>>>(query, keys, embf, w1, b1, w2, b2,
                                        dw1, db1, dw2, db2, ow, ob, out);
    }
}